// Round 7
// baseline (345.176 us; speedup 1.0000x reference)
//
#include <hip/hip_runtime.h>
#include <hip/hip_cooperative_groups.h>
#include <stdint.h>

namespace cg = cooperative_groups;

#define NUM_CLASSES 81
#define MAX_BOXES 300
#define NEG_SCORE (-1000000000.0f)
#define IOU_THR 0.4f
#define MMAX 2048
#define MWORDS (MMAX / 64)     // 32
#define GRID_BLOCKS 256
#define BLOCK_THREADS 256

// ---- workspace layout (bytes) ----
static constexpr size_t OFF_SCORES = 0;               // 300000 * 4 = 1.2 MB
static constexpr size_t OFF_CAREA  = 0x1F0000;        // MMAX f32
static constexpr size_t OFF_COARSE = 0x200000;        // 256 u32
static constexpr size_t OFF_FINE   = 0x201000;        // 256 u32
static constexpr size_t OFF_CTRL   = 0x202000;        // [0]=cand_count [1]=acc_count
static constexpr size_t OFF_KEYS   = 0x208000;        // MMAX u64
static constexpr size_t OFF_CIDX   = 0x210000;        // MMAX int
static constexpr size_t OFF_CBOX   = 0x214000;        // MMAX float4
static constexpr size_t OFF_ACC    = 0x224000;        // 300 int
static constexpr size_t OFF_MATRIX = 0x228000;        // MMAX * MWORDS u64 = 512 KB

__device__ __forceinline__ uint32_t float_ordered(float f) {
    uint32_t b = __float_as_uint(f);
    return (b & 0x80000000u) ? ~b : (b | 0x80000000u);
}

__device__ __forceinline__ uint64_t readlane_u64(uint64_t v, int srclane) {
    uint32_t lo = (uint32_t)__builtin_amdgcn_readlane((int)(uint32_t)v, srclane);
    uint32_t hi = (uint32_t)__builtin_amdgcn_readlane((int)(uint32_t)(v >> 32), srclane);
    return ((uint64_t)hi << 32) | lo;
}

// pick the coarse bin C containing the MMAX-th element; returns -1 if total <= MMAX
__device__ __forceinline__ int select_coarse(const uint32_t* coarse, uint32_t* above_out) {
    uint32_t s = 0;
    for (int c = 255; c >= 0; --c) {
        uint32_t sc = s + coarse[c];
        if (sc > MMAX) { *above_out = s; return c; }
        s = sc;
    }
    *above_out = s;
    return -1;
}

typedef const uint32_t __attribute__((address_space(1)))* glb_u32p;
typedef uint32_t __attribute__((address_space(3)))* lds_u32p;

union SmemU {
    uint32_t h[256];                  // hist phases (1 KB)
    uint64_t kk[MMAX];                // rank phase (16 KB)
    uint64_t sbuf[2][64][MWORDS];     // scan phase (32 KB)
};

__global__ void __launch_bounds__(BLOCK_THREADS) nms_mega(
    const float* __restrict__ boxes, const float* __restrict__ cls,
    float* __restrict__ out, char* __restrict__ ws, int n, int out_total) {
    cg::grid_group grid = cg::this_grid();

    float*     scores      = (float*)(ws + OFF_SCORES);
    float*     careas      = (float*)(ws + OFF_CAREA);
    uint32_t*  coarse      = (uint32_t*)(ws + OFF_COARSE);
    uint32_t*  fine        = (uint32_t*)(ws + OFF_FINE);
    uint32_t*  ctrl        = (uint32_t*)(ws + OFF_CTRL);
    uint64_t*  keys        = (uint64_t*)(ws + OFF_KEYS);
    int*       csorted_idx = (int*)(ws + OFF_CIDX);
    float4*    csorted_box = (float4*)(ws + OFF_CBOX);
    int*       accepted    = (int*)(ws + OFF_ACC);
    uint64_t*  matrix      = (uint64_t*)(ws + OFF_MATRIX);

    __shared__ SmemU sm;
    __shared__ int sC;
    __shared__ uint32_t sThr;

    const int tid = threadIdx.x;
    const int bid = blockIdx.x;
    const int nb  = gridDim.x;

    // ---- P0: init (block 0) + P1: score (all blocks, grid-stride, 16 lanes/box) ----
    if (bid == 0) {
        if (tid < 256) { coarse[tid] = 0; fine[tid] = 0; }
        if (tid < 8) ctrl[tid] = 0;
    }
    {
        const int q = tid & 15;
        const int g = tid >> 4;  // 16 boxes per block-iteration
        for (int b0 = bid * 16; b0 < n; b0 += nb * 16) {
            int box = b0 + g;
            int cbox = box < n ? box : n - 1;
            const float* row = cls + (size_t)cbox * NUM_CLASSES;
            float v[5];
            #pragma unroll
            for (int it = 0; it < 5; ++it) v[it] = row[it * 16 + q];
            float e80 = row[80];
            float m = v[0];
            #pragma unroll
            for (int it = 1; it < 5; ++it) m = fmaxf(m, v[it]);
            m = (q == 15) ? fmaxf(m, e80) : m;
            m = fmaxf(m, __shfl_xor(m, 1));
            m = fmaxf(m, __shfl_xor(m, 2));
            m = fmaxf(m, __shfl_xor(m, 4));
            m = fmaxf(m, __shfl_xor(m, 8));
            if (q == 0 && box < n)
                scores[box] = (v[0] == m) ? NEG_SCORE : m;  // equality => argmax==0
        }
    }
    grid.sync();  // 1

    // ---- P2: coarse 256-bin hist on top-8 ordered bits (LDS aggregate) ----
    for (int t = tid; t < 256; t += BLOCK_THREADS) sm.h[t] = 0;
    __syncthreads();
    for (int i = bid * BLOCK_THREADS + tid; i < n; i += nb * BLOCK_THREADS)
        atomicAdd(&sm.h[float_ordered(scores[i]) >> 24], 1u);
    __syncthreads();
    for (int t = tid; t < 256; t += BLOCK_THREADS)
        if (sm.h[t]) atomicAdd(&coarse[t], sm.h[t]);
    grid.sync();  // 2

    // ---- P3: fine 256-bin hist inside coarse bin C ----
    if (tid == 0) { uint32_t ab; sC = select_coarse(coarse, &ab); }
    for (int t = tid; t < 256; t += BLOCK_THREADS) sm.h[t] = 0;
    __syncthreads();
    {
        int C = sC;
        if (C >= 0) {
            for (int i = bid * BLOCK_THREADS + tid; i < n; i += nb * BLOCK_THREADS) {
                uint32_t o = float_ordered(scores[i]);
                if ((int)(o >> 24) == C) atomicAdd(&sm.h[(o >> 16) & 255u], 1u);
            }
        }
    }
    __syncthreads();
    for (int t = tid; t < 256; t += BLOCK_THREADS)
        if (sm.h[t]) atomicAdd(&fine[t], sm.h[t]);
    grid.sync();  // 3

    // ---- P4: threshold + compact keys = (ordered<<32)|~idx ----
    if (tid == 0) {
        uint32_t above;
        int C = select_coarse(coarse, &above);
        uint32_t thr;
        if (C < 0) {
            thr = 0;
        } else {
            uint32_t R = MMAX - above;
            uint32_t g = 0, F = 0;
            for (int f = 255; f >= 0; --f) {
                uint32_t gf = g + fine[f];
                if (gf > R) { F = (uint32_t)f + 1u; break; }
                g = gf;
            }
            thr = ((uint32_t)C << 8) | F;
        }
        sThr = thr;
    }
    __syncthreads();
    {
        uint32_t thr = sThr;
        for (int i = bid * BLOCK_THREADS + tid; i < n; i += nb * BLOCK_THREADS) {
            uint32_t o = float_ordered(scores[i]);
            if ((o >> 16) >= thr) {
                uint32_t pos = atomicAdd(&ctrl[0], 1u);
                if (pos < MMAX)
                    keys[pos] = ((uint64_t)o << 32) | (uint32_t)(~(uint32_t)i);
            }
        }
    }
    grid.sync();  // 4

    int M = (int)ctrl[0]; if (M > MMAX) M = MMAX;

    // ---- P5: rank + scatter (blocks 0..7; full key set in LDS; no atomics) ----
    if (bid < MMAX / BLOCK_THREADS) {
        for (int i = tid; i < MMAX; i += BLOCK_THREADS)
            sm.kk[i] = (i < M) ? keys[i] : 0ull;  // 0 never exceeds a candidate key
        __syncthreads();
        int c = bid * BLOCK_THREADS + tid;
        if (c < M) {
            uint64_t k = sm.kk[c];
            int cnt = 0;
            #pragma unroll 8
            for (int u = 0; u < MMAX; ++u) cnt += (sm.kk[u] > k) ? 1 : 0;
            uint32_t idx = ~(uint32_t)k;
            float4 b = *(const float4*)(boxes + (size_t)idx * 4);
            csorted_idx[cnt] = (int)idx;
            csorted_box[cnt] = b;
            careas[cnt] = fmaxf(b.z - b.x, 0.f) * fmaxf(b.w - b.y, 0.f);
        }
        __syncthreads();
    }
    grid.sync();  // 5

    // ---- P6: IoU suppression bitmask, upper-triangle words only (w >= i>>6) ----
    {
        int lane = tid & 63;
        int wave = tid >> 6;  // 4 waves per block
        for (int i = bid; i < M; i += nb) {
            float4 bi = csorted_box[i];
            float ai = careas[i];
            int w0 = i >> 6;
            for (int w = w0 + wave; w < MWORDS; w += 4) {
                int j = (w << 6) | lane;
                bool sup = false;
                if (j < M) {
                    float4 bj = csorted_box[j];
                    float xx1 = fmaxf(bi.x, bj.x);
                    float yy1 = fmaxf(bi.y, bj.y);
                    float xx2 = fminf(bi.z, bj.z);
                    float yy2 = fminf(bi.w, bj.w);
                    float inter = fmaxf(xx2 - xx1, 0.f) * fmaxf(yy2 - yy1, 0.f);
                    float uni = ai + careas[j] - inter;
                    float iou = inter / fmaxf(uni, 1e-8f);
                    sup = iou > IOU_THR;
                }
                uint64_t word = __ballot(sup ? 1 : 0);
                if (lane == 0) matrix[(size_t)i * MWORDS + w] = word;
            }
        }
    }
    grid.sync();  // 6

    // ---- P7: sequential greedy scan (block 0, wave 0). LDS-DMA double buffer ----
    if (bid == 0 && tid < 64) {
        const int lane = tid;
        const int l31 = lane & 31;
        uint64_t removed = 0;
        uint64_t wrd = 0;
        int acc = 0;

#define STAGE(BI, BASE)                                                            \
    {                                                                              \
        _Pragma("unroll")                                                          \
        for (int r_ = 0; r_ < 64; ++r_) {                                          \
            const uint32_t* gsrc =                                                 \
                (const uint32_t*)(matrix + (size_t)((BASE) + r_) * MWORDS) + lane; \
            __builtin_amdgcn_global_load_lds((glb_u32p)gsrc,                       \
                                             (lds_u32p)&sm.sbuf[BI][r_][0], 4, 0, 0); \
        }                                                                          \
    }

#define PROCESS(BI, BASE)                                                          \
    {                                                                              \
        uint64_t W[16];                                                            \
        _Pragma("unroll")                                                          \
        for (int w_ = 0; w_ < 16; ++w_) W[w_] = sm.sbuf[BI][w_][l31];              \
        _Pragma("unroll")                                                          \
        for (int r_ = 0; r_ < 64; ++r_) {                                          \
            int i_ = (BASE) + r_;                                                  \
            uint64_t row = W[r_ & 15];                                             \
            if (r_ + 16 < 64) W[r_ & 15] = sm.sbuf[BI][r_ + 16][l31];              \
            if (r_ == 0) wrd = readlane_u64(removed, i_ >> 6);                     \
            if (i_ < M && acc < MAX_BOXES && !((wrd >> (i_ & 63)) & 1ull)) {       \
                if (lane == 0) accepted[acc] = i_;                                 \
                removed |= row;                                                    \
                wrd = readlane_u64(removed, i_ >> 6);                              \
                ++acc;                                                             \
            }                                                                      \
        }                                                                          \
    }

        int nblocks = (M + 63) >> 6;
        if (nblocks > 0) {
            STAGE(0, 0);
            asm volatile("s_waitcnt vmcnt(0)" ::: "memory");
            int bi = 0;
            for (int b = 0; b < nblocks && acc < MAX_BOXES; ++b) {
                if (b + 1 < nblocks) STAGE(bi ^ 1, (b + 1) << 6);
                PROCESS(bi, b << 6);
                asm volatile("s_waitcnt vmcnt(0)" ::: "memory");
                bi ^= 1;
            }
        }
#undef STAGE
#undef PROCESS
        if (lane == 0) ctrl[1] = (uint32_t)acc;
    }
    grid.sync();  // 7

    // ---- P8: write all outputs (zeros for invalid slots) ----
    {
        int acc = (int)ctrl[1];
        for (int e = bid * BLOCK_THREADS + tid; e < out_total; e += nb * BLOCK_THREADS) {
            float val = 0.0f;
            if (e < MAX_BOXES * 4) {
                int s = e >> 2, f = e & 3;
                if (s < acc) {
                    int orig = csorted_idx[accepted[s]];
                    val = boxes[(size_t)orig * 4 + f];
                }
            } else {
                int e2 = e - MAX_BOXES * 4;
                int s = e2 / NUM_CLASSES;
                int c = e2 - s * NUM_CLASSES;
                if (s < acc) {
                    int orig = csorted_idx[accepted[s]];
                    val = cls[(size_t)orig * NUM_CLASSES + c];
                }
            }
            out[e] = val;
        }
    }
}

extern "C" void kernel_launch(void* const* d_in, const int* in_sizes, int n_in,
                              void* d_out, int out_size, void* d_ws, size_t ws_size,
                              hipStream_t stream) {
    const float* boxes = (const float*)d_in[0];
    const float* cls   = (const float*)d_in[1];
    float* out = (float*)d_out;
    char* ws = (char*)d_ws;
    int N = in_sizes[0] / 4;
    int out_total = out_size;

    void* args[] = {(void*)&boxes, (void*)&cls, (void*)&out, (void*)&ws,
                    (void*)&N, (void*)&out_total};
    hipLaunchCooperativeKernel((const void*)nms_mega, dim3(GRID_BLOCKS),
                               dim3(BLOCK_THREADS), args, 0, stream);
}

// Round 8
// 143.725 us; speedup vs baseline: 2.4016x; 2.4016x over previous
//
#include <hip/hip_runtime.h>
#include <stdint.h>

#define NUM_CLASSES 81
#define MAX_BOXES 300
#define NEG_SCORE (-1000000000.0f)
#define IOU_THR 0.4f
#define MMAX 2048
#define MWORDS (MMAX / 64)   // 32

// ---- workspace layout (bytes) ----
static constexpr size_t OFF_SCORES = 0;               // 300000 * 4 = 1.2 MB
static constexpr size_t OFF_CAREA  = 0x1F0000;        // MMAX f32
static constexpr size_t OFF_COARSE = 0x200000;        // 256 u32
static constexpr size_t OFF_FINE   = 0x201000;        // 256 u32
static constexpr size_t OFF_CTRL   = 0x202000;        // [0]=cand_count
static constexpr size_t OFF_KEYS   = 0x208000;        // MMAX u64
static constexpr size_t OFF_CIDX   = 0x210000;        // MMAX int
static constexpr size_t OFF_CBOX   = 0x214000;        // MMAX float4
static constexpr size_t OFF_MATRIX = 0x228000;        // MMAX * MWORDS u64 = 512 KB

__device__ __forceinline__ uint32_t float_ordered(float f) {
    uint32_t b = __float_as_uint(f);
    return (b & 0x80000000u) ? ~b : (b | 0x80000000u);
}

__device__ __forceinline__ uint64_t readlane_u64(uint64_t v, int srclane) {
    uint32_t lo = (uint32_t)__builtin_amdgcn_readlane((int)(uint32_t)v, srclane);
    uint32_t hi = (uint32_t)__builtin_amdgcn_readlane((int)(uint32_t)(v >> 32), srclane);
    return ((uint64_t)hi << 32) | lo;
}

// A: 8 lanes per box, direct coalesced global dword loads, no LDS, no atomics.
// Lane r (0..7) loads row[r], row[8+r], ..., row[72+r] (10 loads, covers 0..79),
// then every lane folds row[80] (same value per box -> idempotent for max).
// 3x shfl_xor reduce within the 8-lane group. Lane r==0 holds row[0] (v[0]) for
// the argmax==0 test and writes the score.
// Block 0 additionally zeroes hists / counters (init fold; no consumer of those
// buffers runs before this kernel completes).
__global__ void score_kernel(const float* __restrict__ cls, float* __restrict__ scores,
                             uint32_t* __restrict__ coarse, uint32_t* __restrict__ fine,
                             uint32_t* __restrict__ ctrl, int n) {
    if (blockIdx.x == 0) {
        int t = threadIdx.x;
        if (t < 256) { coarse[t] = 0; fine[t] = 0; }
        if (t < 8) ctrl[t] = 0;
    }
    const int r = threadIdx.x & 7;
    const int box = blockIdx.x * 32 + (threadIdx.x >> 3);  // 256 thr = 32 boxes/block
    const int cbox = box < n ? box : n - 1;
    const float* row = cls + (size_t)cbox * NUM_CLASSES;

    float v[10];
    #pragma unroll
    for (int it = 0; it < 10; ++it) v[it] = row[it * 8 + r];
    float e80 = row[80];

    float m = v[0];
    #pragma unroll
    for (int it = 1; it < 10; ++it) m = fmaxf(m, v[it]);
    m = fmaxf(m, e80);
    m = fmaxf(m, __shfl_xor(m, 1));
    m = fmaxf(m, __shfl_xor(m, 2));
    m = fmaxf(m, __shfl_xor(m, 4));

    if (r == 0 && box < n) {
        scores[box] = (v[0] == m) ? NEG_SCORE : m;  // v[0]<=m always; equality => argmax==0
    }
}

// B: coarse 256-bin histogram on top-8 ordered bits (LDS aggregate -> global)
__global__ void coarse_hist_kernel(const float* __restrict__ scores, uint32_t* __restrict__ coarse, int n) {
    __shared__ uint32_t h[256];
    for (int t = threadIdx.x; t < 256; t += blockDim.x) h[t] = 0;
    __syncthreads();
    for (int i = blockIdx.x * blockDim.x + threadIdx.x; i < n; i += gridDim.x * blockDim.x) {
        uint32_t o = float_ordered(scores[i]);
        atomicAdd(&h[o >> 24], 1u);
    }
    __syncthreads();
    for (int t = threadIdx.x; t < 256; t += blockDim.x)
        if (h[t]) atomicAdd(&coarse[t], h[t]);
}

// pick the coarse bin C containing the MMAX-th element; returns -1 if total <= MMAX
__device__ __forceinline__ int select_coarse(const uint32_t* coarse, uint32_t* above_out) {
    uint32_t s = 0;
    for (int c = 255; c >= 0; --c) {
        uint32_t sc = s + coarse[c];
        if (sc > MMAX) { *above_out = s; return c; }
        s = sc;
    }
    *above_out = s;
    return -1;
}

// D: fine 256-bin histogram of elements inside coarse bin C (next 8 ordered bits)
__global__ void fine_hist_kernel(const float* __restrict__ scores, const uint32_t* __restrict__ coarse,
                                 uint32_t* __restrict__ fine, int n) {
    __shared__ int sC;
    __shared__ uint32_t h[256];
    if (threadIdx.x == 0) {
        uint32_t above;
        sC = select_coarse(coarse, &above);
    }
    for (int t = threadIdx.x; t < 256; t += blockDim.x) h[t] = 0;
    __syncthreads();
    int C = sC;
    if (C < 0) return;
    for (int i = blockIdx.x * blockDim.x + threadIdx.x; i < n; i += gridDim.x * blockDim.x) {
        uint32_t o = float_ordered(scores[i]);
        if ((int)(o >> 24) == C) atomicAdd(&h[(o >> 16) & 255u], 1u);
    }
    __syncthreads();
    for (int t = threadIdx.x; t < 256; t += blockDim.x)
        if (h[t]) atomicAdd(&fine[t], h[t]);
}

// F: compute 16-bit threshold (<= MMAX candidates), compact keys = (ordered<<32)|~idx
__global__ void compact_kernel(const float* __restrict__ scores, const uint32_t* __restrict__ coarse,
                               const uint32_t* __restrict__ fine, uint32_t* __restrict__ ctrl,
                               uint64_t* __restrict__ keys, int n) {
    __shared__ uint32_t sThr;
    if (threadIdx.x == 0) {
        uint32_t above;
        int C = select_coarse(coarse, &above);
        uint32_t thr;
        if (C < 0) {
            thr = 0;
        } else {
            uint32_t R = MMAX - above;
            uint32_t g = 0, F = 0;
            for (int f = 255; f >= 0; --f) {
                uint32_t gf = g + fine[f];
                if (gf > R) { F = (uint32_t)f + 1u; break; }
                g = gf;
            }
            thr = ((uint32_t)C << 8) | F;
        }
        sThr = thr;
    }
    __syncthreads();
    uint32_t thr = sThr;
    for (int i = blockIdx.x * blockDim.x + threadIdx.x; i < n; i += gridDim.x * blockDim.x) {
        uint32_t o = float_ordered(scores[i]);
        if ((o >> 16) >= thr) {
            uint32_t pos = atomicAdd(&ctrl[0], 1u);
            if (pos < MMAX)
                keys[pos] = ((uint64_t)o << 32) | (uint32_t)(~(uint32_t)i);
        }
    }
}

// G: fused rank + scatter. 8 blocks; each holds ALL keys in LDS, each thread
// counts #{j : key_j > key_c} locally (LDS broadcast reads, no atomics, no rank
// buffer) and scatters its candidate into sorted position.
__global__ void rank_scatter_kernel(const uint64_t* __restrict__ keys, const uint32_t* __restrict__ ctrl,
                                    const float* __restrict__ boxes,
                                    int* __restrict__ csorted_idx, float4* __restrict__ csorted_box,
                                    float* __restrict__ careas) {
    __shared__ uint64_t kk[MMAX];  // 16 KB
    int M = (int)ctrl[0]; if (M > MMAX) M = MMAX;
    int t = threadIdx.x;
    for (int i = t; i < MMAX; i += blockDim.x)
        kk[i] = (i < M) ? keys[i] : 0ull;  // 0 never exceeds a candidate key (top bit set)
    __syncthreads();
    int c = blockIdx.x * blockDim.x + t;
    if (c >= M) return;
    uint64_t k = kk[c];
    int cnt = 0;
    #pragma unroll 8
    for (int u = 0; u < MMAX; ++u) cnt += (kk[u] > k) ? 1 : 0;
    uint32_t idx = ~(uint32_t)k;
    float4 b = *(const float4*)(boxes + (size_t)idx * 4);
    csorted_idx[cnt] = (int)idx;
    csorted_box[cnt] = b;
    careas[cnt] = fmaxf(b.z - b.x, 0.f) * fmaxf(b.w - b.y, 0.f);
}

// H: pairwise IoU suppression bitmask, upper-triangle words only (w >= i>>6).
// Lower words stay unwritten: the scan consults the removed-word only at its
// current (monotone) position, so stale bits in passed words are never read.
__global__ void matrix_kernel(const float4* __restrict__ cbox, const float* __restrict__ careas,
                              const uint32_t* __restrict__ ctrl, uint64_t* __restrict__ matrix) {
    int i = blockIdx.x;
    int M = (int)ctrl[0]; if (M > MMAX) M = MMAX;
    if (i >= M) return;
    int lane = threadIdx.x & 63;
    int wave = threadIdx.x >> 6;  // 4 waves per block
    float4 bi = cbox[i];
    float ai = careas[i];
    int w0 = i >> 6;
    for (int w = w0 + wave; w < MWORDS; w += 4) {
        int j = (w << 6) | lane;
        bool sup = false;
        if (j < M) {
            float4 bj = cbox[j];
            float xx1 = fmaxf(bi.x, bj.x);
            float yy1 = fmaxf(bi.y, bj.y);
            float xx2 = fminf(bi.z, bj.z);
            float yy2 = fminf(bi.w, bj.w);
            float inter = fmaxf(xx2 - xx1, 0.f) * fmaxf(yy2 - yy1, 0.f);
            float uni = ai + careas[j] - inter;
            float iou = inter / fmaxf(uni, 1e-8f);
            sup = iou > IOU_THR;
        }
        uint64_t word = __ballot(sup ? 1 : 0);
        if (lane == 0) matrix[(size_t)i * MWORDS + w] = word;
    }
}

// I+J fused: sequential greedy scan (wave 0) + output write (all 16 waves).
// Scan: removed bitmask in lanes 0..31 (1 u64 each); rows staged to LDS via
// global_load_lds double-buffered 64-row blocks (fire-and-forget DMA, vmcnt-
// counted); consumed through a 16-deep rolling register window. Accepted list
// and count live in LDS; after __syncthreads all 1024 threads gather outputs.
typedef const uint32_t __attribute__((address_space(1)))* glb_u32p;
typedef uint32_t __attribute__((address_space(3)))* lds_u32p;

__global__ void __launch_bounds__(1024) scan_output_kernel(
    const uint64_t* __restrict__ matrix, const uint32_t* __restrict__ ctrl,
    const float* __restrict__ boxes, const float* __restrict__ cls,
    const int* __restrict__ csorted_idx, float* __restrict__ out, int out_total) {
    __shared__ uint64_t sbuf[2][64][MWORDS];  // 32 KB
    __shared__ int s_accepted[MAX_BOXES];
    __shared__ int s_acc;
    int M = (int)ctrl[0]; if (M > MMAX) M = MMAX;

    if (threadIdx.x < 64) {
        const int lane = threadIdx.x;
        const int l31 = lane & 31;
        uint64_t removed = 0;
        uint64_t wrd = 0;
        int acc = 0;

#define STAGE(BI, BASE)                                                            \
    {                                                                              \
        _Pragma("unroll")                                                          \
        for (int r_ = 0; r_ < 64; ++r_) {                                          \
            const uint32_t* gsrc =                                                 \
                (const uint32_t*)(matrix + (size_t)((BASE) + r_) * MWORDS) + lane; \
            __builtin_amdgcn_global_load_lds((glb_u32p)gsrc,                       \
                                             (lds_u32p)&sbuf[BI][r_][0], 4, 0, 0); \
        }                                                                          \
    }

#define PROCESS(BI, BASE)                                                          \
    {                                                                              \
        uint64_t W[16];                                                            \
        _Pragma("unroll")                                                          \
        for (int w_ = 0; w_ < 16; ++w_) W[w_] = sbuf[BI][w_][l31];                 \
        _Pragma("unroll")                                                          \
        for (int r_ = 0; r_ < 64; ++r_) {                                          \
            int i_ = (BASE) + r_;                                                  \
            uint64_t row = W[r_ & 15];                                             \
            if (r_ + 16 < 64) W[r_ & 15] = sbuf[BI][r_ + 16][l31];                 \
            if (r_ == 0) wrd = readlane_u64(removed, i_ >> 6);                     \
            if (i_ < M && acc < MAX_BOXES && !((wrd >> (i_ & 63)) & 1ull)) {       \
                if (lane == 0) s_accepted[acc] = i_;                               \
                removed |= row;                                                    \
                wrd = readlane_u64(removed, i_ >> 6);                              \
                ++acc;                                                             \
            }                                                                      \
        }                                                                          \
    }

        int nblocks = (M + 63) >> 6;
        if (nblocks > 0) {
            STAGE(0, 0);
            asm volatile("s_waitcnt vmcnt(0)" ::: "memory");
            int bi = 0;
            for (int b = 0; b < nblocks && acc < MAX_BOXES; ++b) {
                if (b + 1 < nblocks) STAGE(bi ^ 1, (b + 1) << 6);
                PROCESS(bi, b << 6);
                asm volatile("s_waitcnt vmcnt(0)" ::: "memory");
                bi ^= 1;
            }
        }
#undef STAGE
#undef PROCESS
        if (lane == 0) s_acc = acc;
    }
    __syncthreads();

    int acc = s_acc;
    for (int e = threadIdx.x; e < out_total; e += 1024) {
        float val = 0.0f;
        if (e < MAX_BOXES * 4) {
            int s = e >> 2, f = e & 3;
            if (s < acc) {
                int orig = csorted_idx[s_accepted[s]];
                val = boxes[(size_t)orig * 4 + f];
            }
        } else {
            int e2 = e - MAX_BOXES * 4;
            int s = e2 / NUM_CLASSES;
            int c = e2 - s * NUM_CLASSES;
            if (s < acc) {
                int orig = csorted_idx[s_accepted[s]];
                val = cls[(size_t)orig * NUM_CLASSES + c];
            }
        }
        out[e] = val;
    }
}

extern "C" void kernel_launch(void* const* d_in, const int* in_sizes, int n_in,
                              void* d_out, int out_size, void* d_ws, size_t ws_size,
                              hipStream_t stream) {
    const float* boxes = (const float*)d_in[0];
    const float* cls   = (const float*)d_in[1];
    float* out = (float*)d_out;
    const int N = in_sizes[0] / 4;

    char* ws = (char*)d_ws;
    float*     scores      = (float*)(ws + OFF_SCORES);
    float*     careas      = (float*)(ws + OFF_CAREA);
    uint32_t*  coarse      = (uint32_t*)(ws + OFF_COARSE);
    uint32_t*  fine        = (uint32_t*)(ws + OFF_FINE);
    uint32_t*  ctrl        = (uint32_t*)(ws + OFF_CTRL);
    uint64_t*  keys        = (uint64_t*)(ws + OFF_KEYS);
    int*       csorted_idx = (int*)(ws + OFF_CIDX);
    float4*    csorted_box = (float4*)(ws + OFF_CBOX);
    uint64_t*  matrix      = (uint64_t*)(ws + OFF_MATRIX);

    score_kernel<<<(N + 31) / 32, 256, 0, stream>>>(cls, scores, coarse, fine, ctrl, N);
    coarse_hist_kernel<<<256, 256, 0, stream>>>(scores, coarse, N);
    fine_hist_kernel<<<256, 256, 0, stream>>>(scores, coarse, fine, N);
    compact_kernel<<<512, 256, 0, stream>>>(scores, coarse, fine, ctrl, keys, N);
    rank_scatter_kernel<<<MMAX / 256, 256, 0, stream>>>(keys, ctrl, boxes, csorted_idx,
                                                        csorted_box, careas);
    matrix_kernel<<<MMAX, 256, 0, stream>>>(csorted_box, careas, ctrl, matrix);
    scan_output_kernel<<<1, 1024, 0, stream>>>(matrix, ctrl, boxes, cls, csorted_idx,
                                               out, out_size);
}

// Round 9
// 131.387 us; speedup vs baseline: 2.6272x; 1.0939x over previous
//
#include <hip/hip_runtime.h>
#include <stdint.h>

#define NUM_CLASSES 81
#define MAX_BOXES 300
#define NEG_SCORE (-1000000000.0f)
#define IOU_THR 0.4f
#define MMAX 2048
#define MWORDS (MMAX / 64)   // 32

// ---- workspace layout (bytes) ----
static constexpr size_t OFF_SCORES = 0;               // 300000 * 4 = 1.2 MB
static constexpr size_t OFF_CAREA  = 0x1F0000;        // MMAX f32
static constexpr size_t OFF_COARSE = 0x200000;        // 256 u32
static constexpr size_t OFF_FINE   = 0x201000;        // 256 u32
static constexpr size_t OFF_CTRL   = 0x202000;        // [0]=cand_count [1]=acc_count
static constexpr size_t OFF_KEYS   = 0x208000;        // MMAX u64
static constexpr size_t OFF_CIDX   = 0x210000;        // MMAX int
static constexpr size_t OFF_CBOX   = 0x214000;        // MMAX float4
static constexpr size_t OFF_ACC    = 0x224000;        // 300 int
static constexpr size_t OFF_MATRIX = 0x228000;        // MMAX * MWORDS u64 = 512 KB

__device__ __forceinline__ uint32_t float_ordered(float f) {
    uint32_t b = __float_as_uint(f);
    return (b & 0x80000000u) ? ~b : (b | 0x80000000u);
}

__device__ __forceinline__ uint64_t readlane_u64(uint64_t v, int srclane) {
    uint32_t lo = (uint32_t)__builtin_amdgcn_readlane((int)(uint32_t)v, srclane);
    uint32_t hi = (uint32_t)__builtin_amdgcn_readlane((int)(uint32_t)(v >> 32), srclane);
    return ((uint64_t)hi << 32) | lo;
}

// A: 8 lanes per box, direct coalesced global dword loads, no LDS, no atomics.
// Lane r (0..7) loads row[r], row[8+r], ..., row[72+r] (10 loads, covers 0..79),
// then every lane folds row[80] (same value per box -> idempotent for max).
// 3x shfl_xor reduce within the 8-lane group. Lane r==0 holds row[0] (v[0]) for
// the argmax==0 test and writes the score.
// Block 0 additionally zeroes hists / counters (init fold).
__global__ void score_kernel(const float* __restrict__ cls, float* __restrict__ scores,
                             uint32_t* __restrict__ coarse, uint32_t* __restrict__ fine,
                             uint32_t* __restrict__ ctrl, int n) {
    if (blockIdx.x == 0) {
        int t = threadIdx.x;
        if (t < 256) { coarse[t] = 0; fine[t] = 0; }
        if (t < 8) ctrl[t] = 0;
    }
    const int r = threadIdx.x & 7;
    const int box = blockIdx.x * 32 + (threadIdx.x >> 3);  // 256 thr = 32 boxes/block
    const int cbox = box < n ? box : n - 1;
    const float* row = cls + (size_t)cbox * NUM_CLASSES;

    float v[10];
    #pragma unroll
    for (int it = 0; it < 10; ++it) v[it] = row[it * 8 + r];
    float e80 = row[80];

    float m = v[0];
    #pragma unroll
    for (int it = 1; it < 10; ++it) m = fmaxf(m, v[it]);
    m = fmaxf(m, e80);
    m = fmaxf(m, __shfl_xor(m, 1));
    m = fmaxf(m, __shfl_xor(m, 2));
    m = fmaxf(m, __shfl_xor(m, 4));

    if (r == 0 && box < n) {
        scores[box] = (v[0] == m) ? NEG_SCORE : m;  // v[0]<=m always; equality => argmax==0
    }
}

// B: coarse 256-bin histogram on top-8 ordered bits (LDS aggregate -> global)
__global__ void coarse_hist_kernel(const float* __restrict__ scores, uint32_t* __restrict__ coarse, int n) {
    __shared__ uint32_t h[256];
    for (int t = threadIdx.x; t < 256; t += blockDim.x) h[t] = 0;
    __syncthreads();
    for (int i = blockIdx.x * blockDim.x + threadIdx.x; i < n; i += gridDim.x * blockDim.x) {
        uint32_t o = float_ordered(scores[i]);
        atomicAdd(&h[o >> 24], 1u);
    }
    __syncthreads();
    for (int t = threadIdx.x; t < 256; t += blockDim.x)
        if (h[t]) atomicAdd(&coarse[t], h[t]);
}

// pick the coarse bin C containing the MMAX-th element; returns -1 if total <= MMAX
__device__ __forceinline__ int select_coarse(const uint32_t* coarse, uint32_t* above_out) {
    uint32_t s = 0;
    for (int c = 255; c >= 0; --c) {
        uint32_t sc = s + coarse[c];
        if (sc > MMAX) { *above_out = s; return c; }
        s = sc;
    }
    *above_out = s;
    return -1;
}

// D: fine 256-bin histogram of elements inside coarse bin C (next 8 ordered bits)
__global__ void fine_hist_kernel(const float* __restrict__ scores, const uint32_t* __restrict__ coarse,
                                 uint32_t* __restrict__ fine, int n) {
    __shared__ int sC;
    __shared__ uint32_t h[256];
    if (threadIdx.x == 0) {
        uint32_t above;
        sC = select_coarse(coarse, &above);
    }
    for (int t = threadIdx.x; t < 256; t += blockDim.x) h[t] = 0;
    __syncthreads();
    int C = sC;
    if (C < 0) return;
    for (int i = blockIdx.x * blockDim.x + threadIdx.x; i < n; i += gridDim.x * blockDim.x) {
        uint32_t o = float_ordered(scores[i]);
        if ((int)(o >> 24) == C) atomicAdd(&h[(o >> 16) & 255u], 1u);
    }
    __syncthreads();
    for (int t = threadIdx.x; t < 256; t += blockDim.x)
        if (h[t]) atomicAdd(&fine[t], h[t]);
}

// F: compute 16-bit threshold (<= MMAX candidates), compact keys = (ordered<<32)|~idx
__global__ void compact_kernel(const float* __restrict__ scores, const uint32_t* __restrict__ coarse,
                               const uint32_t* __restrict__ fine, uint32_t* __restrict__ ctrl,
                               uint64_t* __restrict__ keys, int n) {
    __shared__ uint32_t sThr;
    if (threadIdx.x == 0) {
        uint32_t above;
        int C = select_coarse(coarse, &above);
        uint32_t thr;
        if (C < 0) {
            thr = 0;
        } else {
            uint32_t R = MMAX - above;
            uint32_t g = 0, F = 0;
            for (int f = 255; f >= 0; --f) {
                uint32_t gf = g + fine[f];
                if (gf > R) { F = (uint32_t)f + 1u; break; }
                g = gf;
            }
            thr = ((uint32_t)C << 8) | F;
        }
        sThr = thr;
    }
    __syncthreads();
    uint32_t thr = sThr;
    for (int i = blockIdx.x * blockDim.x + threadIdx.x; i < n; i += gridDim.x * blockDim.x) {
        uint32_t o = float_ordered(scores[i]);
        if ((o >> 16) >= thr) {
            uint32_t pos = atomicAdd(&ctrl[0], 1u);
            if (pos < MMAX)
                keys[pos] = ((uint64_t)o << 32) | (uint32_t)(~(uint32_t)i);
        }
    }
}

// G: fused rank + scatter. 8 blocks; each holds ALL keys in LDS, each thread
// counts #{j : key_j > key_c} locally (LDS broadcast reads, no atomics, no rank
// buffer) and scatters its candidate into sorted position.
__global__ void rank_scatter_kernel(const uint64_t* __restrict__ keys, const uint32_t* __restrict__ ctrl,
                                    const float* __restrict__ boxes,
                                    int* __restrict__ csorted_idx, float4* __restrict__ csorted_box,
                                    float* __restrict__ careas) {
    __shared__ uint64_t kk[MMAX];  // 16 KB
    int M = (int)ctrl[0]; if (M > MMAX) M = MMAX;
    int t = threadIdx.x;
    for (int i = t; i < MMAX; i += blockDim.x)
        kk[i] = (i < M) ? keys[i] : 0ull;  // 0 never exceeds a candidate key (top bit set)
    __syncthreads();
    int c = blockIdx.x * blockDim.x + t;
    if (c >= M) return;
    uint64_t k = kk[c];
    int cnt = 0;
    #pragma unroll 8
    for (int u = 0; u < MMAX; ++u) cnt += (kk[u] > k) ? 1 : 0;
    uint32_t idx = ~(uint32_t)k;
    float4 b = *(const float4*)(boxes + (size_t)idx * 4);
    csorted_idx[cnt] = (int)idx;
    csorted_box[cnt] = b;
    careas[cnt] = fmaxf(b.z - b.x, 0.f) * fmaxf(b.w - b.y, 0.f);
}

// H: pairwise IoU suppression bitmask, upper-triangle words only (w >= i>>6).
__global__ void matrix_kernel(const float4* __restrict__ cbox, const float* __restrict__ careas,
                              const uint32_t* __restrict__ ctrl, uint64_t* __restrict__ matrix) {
    int i = blockIdx.x;
    int M = (int)ctrl[0]; if (M > MMAX) M = MMAX;
    if (i >= M) return;
    int lane = threadIdx.x & 63;
    int wave = threadIdx.x >> 6;  // 4 waves per block
    float4 bi = cbox[i];
    float ai = careas[i];
    int w0 = i >> 6;
    for (int w = w0 + wave; w < MWORDS; w += 4) {
        int j = (w << 6) | lane;
        bool sup = false;
        if (j < M) {
            float4 bj = cbox[j];
            float xx1 = fmaxf(bi.x, bj.x);
            float yy1 = fmaxf(bi.y, bj.y);
            float xx2 = fminf(bi.z, bj.z);
            float yy2 = fminf(bi.w, bj.w);
            float inter = fmaxf(xx2 - xx1, 0.f) * fmaxf(yy2 - yy1, 0.f);
            float uni = ai + careas[j] - inter;
            float iou = inter / fmaxf(uni, 1e-8f);
            sup = iou > IOU_THR;
        }
        uint64_t word = __ballot(sup ? 1 : 0);
        if (lane == 0) matrix[(size_t)i * MWORDS + w] = word;
    }
}

// I: sequential greedy scan, one wave, OWN kernel with launch_bounds(64) so the
// 16-deep register window cannot be VGPR-capped (round-8 lesson: fusing this
// with a 1024-thread output phase capped VGPRs -> scratch spill -> 35us loss).
// Rows staged to LDS via global_load_lds double-buffered 64-row blocks.
typedef const uint32_t __attribute__((address_space(1)))* glb_u32p;
typedef uint32_t __attribute__((address_space(3)))* lds_u32p;

__global__ void __launch_bounds__(64) scan_kernel(
    const uint64_t* __restrict__ matrix, uint32_t* __restrict__ ctrl,
    int* __restrict__ accepted) {
    __shared__ uint64_t sbuf[2][64][MWORDS];  // 32 KB
    const int lane = threadIdx.x;
    const int l31 = lane & 31;
    int M = (int)ctrl[0]; if (M > MMAX) M = MMAX;
    uint64_t removed = 0;
    uint64_t wrd = 0;
    int acc = 0;

#define STAGE(BI, BASE)                                                            \
    {                                                                              \
        _Pragma("unroll")                                                          \
        for (int r_ = 0; r_ < 64; ++r_) {                                          \
            const uint32_t* gsrc =                                                 \
                (const uint32_t*)(matrix + (size_t)((BASE) + r_) * MWORDS) + lane; \
            __builtin_amdgcn_global_load_lds((glb_u32p)gsrc,                       \
                                             (lds_u32p)&sbuf[BI][r_][0], 4, 0, 0); \
        }                                                                          \
    }

#define PROCESS(BI, BASE)                                                          \
    {                                                                              \
        uint64_t W[16];                                                            \
        _Pragma("unroll")                                                          \
        for (int w_ = 0; w_ < 16; ++w_) W[w_] = sbuf[BI][w_][l31];                 \
        _Pragma("unroll")                                                          \
        for (int r_ = 0; r_ < 64; ++r_) {                                          \
            int i_ = (BASE) + r_;                                                  \
            uint64_t row = W[r_ & 15];                                             \
            if (r_ + 16 < 64) W[r_ & 15] = sbuf[BI][r_ + 16][l31];                 \
            if (r_ == 0) wrd = readlane_u64(removed, i_ >> 6);                     \
            if (i_ < M && acc < MAX_BOXES && !((wrd >> (i_ & 63)) & 1ull)) {       \
                if (lane == 0) accepted[acc] = i_;                                 \
                removed |= row;                                                    \
                wrd = readlane_u64(removed, i_ >> 6);                              \
                ++acc;                                                             \
            }                                                                      \
        }                                                                          \
    }

    int nblocks = (M + 63) >> 6;
    if (nblocks > 0) {
        STAGE(0, 0);
        asm volatile("s_waitcnt vmcnt(0)" ::: "memory");
        int bi = 0;
        for (int b = 0; b < nblocks && acc < MAX_BOXES; ++b) {
            if (b + 1 < nblocks) STAGE(bi ^ 1, (b + 1) << 6);
            PROCESS(bi, b << 6);
            asm volatile("s_waitcnt vmcnt(0)" ::: "memory");
            bi ^= 1;
        }
    }
#undef STAGE
#undef PROCESS
    if (lane == 0) ctrl[1] = (uint32_t)acc;
}

// J: write all 25500 outputs (zeros for invalid slots), 100 blocks
__global__ void output_kernel(const float* __restrict__ boxes, const float* __restrict__ cls,
                              const int* __restrict__ csorted_idx, const int* __restrict__ accepted,
                              const uint32_t* __restrict__ ctrl, float* __restrict__ out, int total) {
    int e = blockIdx.x * blockDim.x + threadIdx.x;
    if (e >= total) return;
    int acc = (int)ctrl[1];
    float val = 0.0f;
    if (e < MAX_BOXES * 4) {
        int s = e >> 2, f = e & 3;
        if (s < acc) {
            int orig = csorted_idx[accepted[s]];
            val = boxes[(size_t)orig * 4 + f];
        }
    } else {
        int e2 = e - MAX_BOXES * 4;
        int s = e2 / NUM_CLASSES;
        int c = e2 - s * NUM_CLASSES;
        if (s < acc) {
            int orig = csorted_idx[accepted[s]];
            val = cls[(size_t)orig * NUM_CLASSES + c];
        }
    }
    out[e] = val;
}

extern "C" void kernel_launch(void* const* d_in, const int* in_sizes, int n_in,
                              void* d_out, int out_size, void* d_ws, size_t ws_size,
                              hipStream_t stream) {
    const float* boxes = (const float*)d_in[0];
    const float* cls   = (const float*)d_in[1];
    float* out = (float*)d_out;
    const int N = in_sizes[0] / 4;

    char* ws = (char*)d_ws;
    float*     scores      = (float*)(ws + OFF_SCORES);
    float*     careas      = (float*)(ws + OFF_CAREA);
    uint32_t*  coarse      = (uint32_t*)(ws + OFF_COARSE);
    uint32_t*  fine        = (uint32_t*)(ws + OFF_FINE);
    uint32_t*  ctrl        = (uint32_t*)(ws + OFF_CTRL);
    uint64_t*  keys        = (uint64_t*)(ws + OFF_KEYS);
    int*       csorted_idx = (int*)(ws + OFF_CIDX);
    float4*    csorted_box = (float4*)(ws + OFF_CBOX);
    int*       accepted    = (int*)(ws + OFF_ACC);
    uint64_t*  matrix      = (uint64_t*)(ws + OFF_MATRIX);

    score_kernel<<<(N + 31) / 32, 256, 0, stream>>>(cls, scores, coarse, fine, ctrl, N);
    coarse_hist_kernel<<<256, 256, 0, stream>>>(scores, coarse, N);
    fine_hist_kernel<<<256, 256, 0, stream>>>(scores, coarse, fine, N);
    compact_kernel<<<512, 256, 0, stream>>>(scores, coarse, fine, ctrl, keys, N);
    rank_scatter_kernel<<<MMAX / 256, 256, 0, stream>>>(keys, ctrl, boxes, csorted_idx,
                                                        csorted_box, careas);
    matrix_kernel<<<MMAX, 256, 0, stream>>>(csorted_box, careas, ctrl, matrix);
    scan_kernel<<<1, 64, 0, stream>>>(matrix, ctrl, accepted);
    output_kernel<<<(out_size + 255) / 256, 256, 0, stream>>>(boxes, cls, csorted_idx, accepted,
                                                              ctrl, out, out_size);
}

// Round 10
// 108.599 us; speedup vs baseline: 3.1785x; 1.2098x over previous
//
#include <hip/hip_runtime.h>
#include <stdint.h>

#define NUM_CLASSES 81
#define MAX_BOXES 300
#define NEG_SCORE (-1000000000.0f)
#define IOU_THR 0.4f
#define MMAX 2048
#define MWORDS (MMAX / 64)   // 32

// ---- workspace layout (bytes) ----
static constexpr size_t OFF_SCORES = 0;               // 300000 * 4 = 1.2 MB
static constexpr size_t OFF_CAREA  = 0x1F0000;        // MMAX f32
static constexpr size_t OFF_COARSE = 0x200000;        // 256 u32
static constexpr size_t OFF_FINE   = 0x201000;        // 256 u32
static constexpr size_t OFF_CTRL   = 0x202000;        // [0]=cand_count [1]=acc_count
static constexpr size_t OFF_RANK   = 0x203000;        // MMAX u32
static constexpr size_t OFF_KEYS   = 0x208000;        // MMAX u64
static constexpr size_t OFF_CIDX   = 0x210000;        // MMAX int
static constexpr size_t OFF_CBOX   = 0x214000;        // MMAX float4
static constexpr size_t OFF_ACC    = 0x224000;        // 300 int
static constexpr size_t OFF_MATRIX = 0x228000;        // MMAX * MWORDS u64 = 512 KB

__device__ __forceinline__ uint32_t float_ordered(float f) {
    uint32_t b = __float_as_uint(f);
    return (b & 0x80000000u) ? ~b : (b | 0x80000000u);
}

__device__ __forceinline__ uint64_t readlane_u64(uint64_t v, int srclane) {
    uint32_t lo = (uint32_t)__builtin_amdgcn_readlane((int)(uint32_t)v, srclane);
    uint32_t hi = (uint32_t)__builtin_amdgcn_readlane((int)(uint32_t)(v >> 32), srclane);
    return ((uint64_t)hi << 32) | lo;
}

// A: 16 lanes per box, direct coalesced global dword loads, no LDS, no atomics.
// (round-6 proven config; round-8's 8-lane variant regressed ~20us — reverted)
// Lane q reads elements q, q+16, ..., q+64 (5 independent loads); lane 15 folds
// element 80. 4x shfl_xor reduce -> box max across the 16-lane group. Lane q==0
// holds element 0 (v[0]) for the argmax==0 test and writes the score.
// Block 0 additionally zeroes hists / counters / ranks (init fold).
__global__ void score_kernel(const float* __restrict__ cls, float* __restrict__ scores,
                             uint32_t* __restrict__ coarse, uint32_t* __restrict__ fine,
                             uint32_t* __restrict__ ctrl, uint32_t* __restrict__ rank, int n) {
    if (blockIdx.x == 0) {
        int t = threadIdx.x;
        if (t < 256) { coarse[t] = 0; fine[t] = 0; }
        if (t < 8) ctrl[t] = 0;
        for (int r = t; r < MMAX; r += 256) rank[r] = 0;
    }
    const int q = threadIdx.x & 15;
    const int box = blockIdx.x * 16 + (threadIdx.x >> 4);  // 256 thr = 16 boxes/block
    const int cbox = box < n ? box : n - 1;
    const float* row = cls + (size_t)cbox * NUM_CLASSES;

    float v[5];
    #pragma unroll
    for (int it = 0; it < 5; ++it) v[it] = row[it * 16 + q];
    float e80 = row[80];

    float m = v[0];
    #pragma unroll
    for (int it = 1; it < 5; ++it) m = fmaxf(m, v[it]);
    m = (q == 15) ? fmaxf(m, e80) : m;
    m = fmaxf(m, __shfl_xor(m, 1));
    m = fmaxf(m, __shfl_xor(m, 2));
    m = fmaxf(m, __shfl_xor(m, 4));
    m = fmaxf(m, __shfl_xor(m, 8));

    if (q == 0 && box < n) {
        scores[box] = (v[0] == m) ? NEG_SCORE : m;  // v[0]<=m always; equality => argmax==0
    }
}

// B: coarse 256-bin histogram on top-8 ordered bits (LDS aggregate -> global)
__global__ void coarse_hist_kernel(const float* __restrict__ scores, uint32_t* __restrict__ coarse, int n) {
    __shared__ uint32_t h[256];
    for (int t = threadIdx.x; t < 256; t += blockDim.x) h[t] = 0;
    __syncthreads();
    for (int i = blockIdx.x * blockDim.x + threadIdx.x; i < n; i += gridDim.x * blockDim.x) {
        uint32_t o = float_ordered(scores[i]);
        atomicAdd(&h[o >> 24], 1u);
    }
    __syncthreads();
    for (int t = threadIdx.x; t < 256; t += blockDim.x)
        if (h[t]) atomicAdd(&coarse[t], h[t]);
}

// pick the coarse bin C containing the MMAX-th element; returns -1 if total <= MMAX
__device__ __forceinline__ int select_coarse(const uint32_t* coarse, uint32_t* above_out) {
    uint32_t s = 0;
    for (int c = 255; c >= 0; --c) {
        uint32_t sc = s + coarse[c];
        if (sc > MMAX) { *above_out = s; return c; }
        s = sc;
    }
    *above_out = s;
    return -1;
}

// D: fine 256-bin histogram of elements inside coarse bin C (next 8 ordered bits)
__global__ void fine_hist_kernel(const float* __restrict__ scores, const uint32_t* __restrict__ coarse,
                                 uint32_t* __restrict__ fine, int n) {
    __shared__ int sC;
    __shared__ uint32_t h[256];
    if (threadIdx.x == 0) {
        uint32_t above;
        sC = select_coarse(coarse, &above);
    }
    for (int t = threadIdx.x; t < 256; t += blockDim.x) h[t] = 0;
    __syncthreads();
    int C = sC;
    if (C < 0) return;
    for (int i = blockIdx.x * blockDim.x + threadIdx.x; i < n; i += gridDim.x * blockDim.x) {
        uint32_t o = float_ordered(scores[i]);
        if ((int)(o >> 24) == C) atomicAdd(&h[(o >> 16) & 255u], 1u);
    }
    __syncthreads();
    for (int t = threadIdx.x; t < 256; t += blockDim.x)
        if (h[t]) atomicAdd(&fine[t], h[t]);
}

// F: compute 16-bit threshold (<= MMAX candidates), compact keys = (ordered<<32)|~idx
__global__ void compact_kernel(const float* __restrict__ scores, const uint32_t* __restrict__ coarse,
                               const uint32_t* __restrict__ fine, uint32_t* __restrict__ ctrl,
                               uint64_t* __restrict__ keys, int n) {
    __shared__ uint32_t sThr;
    if (threadIdx.x == 0) {
        uint32_t above;
        int C = select_coarse(coarse, &above);
        uint32_t thr;
        if (C < 0) {
            thr = 0;
        } else {
            uint32_t R = MMAX - above;
            uint32_t g = 0, F = 0;
            for (int f = 255; f >= 0; --f) {
                uint32_t gf = g + fine[f];
                if (gf > R) { F = (uint32_t)f + 1u; break; }
                g = gf;
            }
            thr = ((uint32_t)C << 8) | F;
        }
        sThr = thr;
    }
    __syncthreads();
    uint32_t thr = sThr;
    for (int i = blockIdx.x * blockDim.x + threadIdx.x; i < n; i += gridDim.x * blockDim.x) {
        uint32_t o = float_ordered(scores[i]);
        if ((o >> 16) >= thr) {
            uint32_t pos = atomicAdd(&ctrl[0], 1u);
            if (pos < MMAX)
                keys[pos] = ((uint64_t)o << 32) | (uint32_t)(~(uint32_t)i);
        }
    }
}

// G1: brute-force rank: rank[c] = #{j : key_j > key_c}, tiled 256x256 via LDS
// (round-6 proven split; 8-block fused LDS-walk variant regressed — reverted)
__global__ void rank_partial_kernel(const uint64_t* __restrict__ keys, const uint32_t* __restrict__ ctrl,
                                    uint32_t* __restrict__ rank) {
    __shared__ uint64_t kk[256];
    int M = (int)ctrl[0]; if (M > MMAX) M = MMAX;
    int cbase = blockIdx.x * 256;
    int jbase = blockIdx.y * 256;
    if (cbase >= M || jbase >= M) return;
    int t = threadIdx.x;
    int j = jbase + t;
    kk[t] = (j < M) ? keys[j] : 0ull;  // 0 never exceeds a candidate key (top bit set)
    __syncthreads();
    int c = cbase + t;
    if (c >= M) return;
    uint64_t k = keys[c];
    int cnt = 0;
    #pragma unroll 8
    for (int u = 0; u < 256; ++u) cnt += (kk[u] > k) ? 1 : 0;
    if (cnt) atomicAdd(&rank[c], (uint32_t)cnt);
}

// G2: scatter into sorted order; gather candidate boxes + areas
__global__ void scatter_kernel(const uint64_t* __restrict__ keys, const uint32_t* __restrict__ rank,
                               const uint32_t* __restrict__ ctrl, const float* __restrict__ boxes,
                               int* __restrict__ csorted_idx, float4* __restrict__ csorted_box,
                               float* __restrict__ careas) {
    int M = (int)ctrl[0]; if (M > MMAX) M = MMAX;
    int c = blockIdx.x * blockDim.x + threadIdx.x;
    if (c >= M) return;
    uint64_t k = keys[c];
    uint32_t r = rank[c];
    uint32_t idx = ~(uint32_t)k;
    float4 b = *(const float4*)(boxes + (size_t)idx * 4);
    csorted_idx[r] = (int)idx;
    csorted_box[r] = b;
    careas[r] = fmaxf(b.z - b.x, 0.f) * fmaxf(b.w - b.y, 0.f);
}

// H: pairwise IoU suppression bitmask, upper-triangle words only (w >= i>>6).
// Lower words stay unwritten: the scan consults the removed-word only at its
// current (monotone) position, so stale bits in passed words are never read.
__global__ void matrix_kernel(const float4* __restrict__ cbox, const float* __restrict__ careas,
                              const uint32_t* __restrict__ ctrl, uint64_t* __restrict__ matrix) {
    int i = blockIdx.x;
    int M = (int)ctrl[0]; if (M > MMAX) M = MMAX;
    if (i >= M) return;
    int lane = threadIdx.x & 63;
    int wave = threadIdx.x >> 6;  // 4 waves per block
    float4 bi = cbox[i];
    float ai = careas[i];
    int w0 = i >> 6;
    for (int w = w0 + wave; w < MWORDS; w += 4) {
        int j = (w << 6) | lane;
        bool sup = false;
        if (j < M) {
            float4 bj = cbox[j];
            float xx1 = fmaxf(bi.x, bj.x);
            float yy1 = fmaxf(bi.y, bj.y);
            float xx2 = fminf(bi.z, bj.z);
            float yy2 = fminf(bi.w, bj.w);
            float inter = fmaxf(xx2 - xx1, 0.f) * fmaxf(yy2 - yy1, 0.f);
            float uni = ai + careas[j] - inter;
            float iou = inter / fmaxf(uni, 1e-8f);
            sup = iou > IOU_THR;
        }
        uint64_t word = __ballot(sup ? 1 : 0);
        if (lane == 0) matrix[(size_t)i * MWORDS + w] = word;
    }
}

// I: sequential greedy scan, one wave, own kernel, launch_bounds(64) so the
// 16-deep register window cannot be VGPR-capped (round-8 lesson). Rows staged
// to LDS via global_load_lds double-buffered 64-row blocks (fire-and-forget
// DMA, vmcnt-counted); consumed through a rolling register window.
typedef const uint32_t __attribute__((address_space(1)))* glb_u32p;
typedef uint32_t __attribute__((address_space(3)))* lds_u32p;

__global__ void __launch_bounds__(64) scan_kernel(
    const uint64_t* __restrict__ matrix, uint32_t* __restrict__ ctrl,
    int* __restrict__ accepted) {
    __shared__ uint64_t sbuf[2][64][MWORDS];  // 32 KB
    const int lane = threadIdx.x;
    const int l31 = lane & 31;
    int M = (int)ctrl[0]; if (M > MMAX) M = MMAX;
    uint64_t removed = 0;
    uint64_t wrd = 0;
    int acc = 0;

#define STAGE(BI, BASE)                                                            \
    {                                                                              \
        _Pragma("unroll")                                                          \
        for (int r_ = 0; r_ < 64; ++r_) {                                          \
            const uint32_t* gsrc =                                                 \
                (const uint32_t*)(matrix + (size_t)((BASE) + r_) * MWORDS) + lane; \
            __builtin_amdgcn_global_load_lds((glb_u32p)gsrc,                       \
                                             (lds_u32p)&sbuf[BI][r_][0], 4, 0, 0); \
        }                                                                          \
    }

#define PROCESS(BI, BASE)                                                          \
    {                                                                              \
        uint64_t W[16];                                                            \
        _Pragma("unroll")                                                          \
        for (int w_ = 0; w_ < 16; ++w_) W[w_] = sbuf[BI][w_][l31];                 \
        _Pragma("unroll")                                                          \
        for (int r_ = 0; r_ < 64; ++r_) {                                          \
            int i_ = (BASE) + r_;                                                  \
            uint64_t row = W[r_ & 15];                                             \
            if (r_ + 16 < 64) W[r_ & 15] = sbuf[BI][r_ + 16][l31];                 \
            if (r_ == 0) wrd = readlane_u64(removed, i_ >> 6);                     \
            if (i_ < M && acc < MAX_BOXES && !((wrd >> (i_ & 63)) & 1ull)) {       \
                if (lane == 0) accepted[acc] = i_;                                 \
                removed |= row;                                                    \
                wrd = readlane_u64(removed, i_ >> 6);                              \
                ++acc;                                                             \
            }                                                                      \
        }                                                                          \
    }

    int nblocks = (M + 63) >> 6;
    if (nblocks > 0) {
        STAGE(0, 0);
        asm volatile("s_waitcnt vmcnt(0)" ::: "memory");
        int bi = 0;
        for (int b = 0; b < nblocks && acc < MAX_BOXES; ++b) {
            if (b + 1 < nblocks) STAGE(bi ^ 1, (b + 1) << 6);
            PROCESS(bi, b << 6);
            asm volatile("s_waitcnt vmcnt(0)" ::: "memory");
            bi ^= 1;
        }
    }
#undef STAGE
#undef PROCESS
    if (lane == 0) ctrl[1] = (uint32_t)acc;
}

// J: write all 25500 outputs (zeros for invalid slots), 100 blocks
__global__ void output_kernel(const float* __restrict__ boxes, const float* __restrict__ cls,
                              const int* __restrict__ csorted_idx, const int* __restrict__ accepted,
                              const uint32_t* __restrict__ ctrl, float* __restrict__ out, int total) {
    int e = blockIdx.x * blockDim.x + threadIdx.x;
    if (e >= total) return;
    int acc = (int)ctrl[1];
    float val = 0.0f;
    if (e < MAX_BOXES * 4) {
        int s = e >> 2, f = e & 3;
        if (s < acc) {
            int orig = csorted_idx[accepted[s]];
            val = boxes[(size_t)orig * 4 + f];
        }
    } else {
        int e2 = e - MAX_BOXES * 4;
        int s = e2 / NUM_CLASSES;
        int c = e2 - s * NUM_CLASSES;
        if (s < acc) {
            int orig = csorted_idx[accepted[s]];
            val = cls[(size_t)orig * NUM_CLASSES + c];
        }
    }
    out[e] = val;
}

extern "C" void kernel_launch(void* const* d_in, const int* in_sizes, int n_in,
                              void* d_out, int out_size, void* d_ws, size_t ws_size,
                              hipStream_t stream) {
    const float* boxes = (const float*)d_in[0];
    const float* cls   = (const float*)d_in[1];
    float* out = (float*)d_out;
    const int N = in_sizes[0] / 4;

    char* ws = (char*)d_ws;
    float*     scores      = (float*)(ws + OFF_SCORES);
    float*     careas      = (float*)(ws + OFF_CAREA);
    uint32_t*  coarse      = (uint32_t*)(ws + OFF_COARSE);
    uint32_t*  fine        = (uint32_t*)(ws + OFF_FINE);
    uint32_t*  ctrl        = (uint32_t*)(ws + OFF_CTRL);
    uint32_t*  rank        = (uint32_t*)(ws + OFF_RANK);
    uint64_t*  keys        = (uint64_t*)(ws + OFF_KEYS);
    int*       csorted_idx = (int*)(ws + OFF_CIDX);
    float4*    csorted_box = (float4*)(ws + OFF_CBOX);
    int*       accepted    = (int*)(ws + OFF_ACC);
    uint64_t*  matrix      = (uint64_t*)(ws + OFF_MATRIX);

    score_kernel<<<(N + 15) / 16, 256, 0, stream>>>(cls, scores, coarse, fine, ctrl, rank, N);
    coarse_hist_kernel<<<256, 256, 0, stream>>>(scores, coarse, N);
    fine_hist_kernel<<<256, 256, 0, stream>>>(scores, coarse, fine, N);
    compact_kernel<<<512, 256, 0, stream>>>(scores, coarse, fine, ctrl, keys, N);
    rank_partial_kernel<<<dim3(MMAX / 256, MMAX / 256), 256, 0, stream>>>(keys, ctrl, rank);
    scatter_kernel<<<MMAX / 256, 256, 0, stream>>>(keys, rank, ctrl, boxes, csorted_idx,
                                                   csorted_box, careas);
    matrix_kernel<<<MMAX, 256, 0, stream>>>(csorted_box, careas, ctrl, matrix);
    scan_kernel<<<1, 64, 0, stream>>>(matrix, ctrl, accepted);
    output_kernel<<<(out_size + 255) / 256, 256, 0, stream>>>(boxes, cls, csorted_idx, accepted,
                                                              ctrl, out, out_size);
}